// Round 3
// baseline (2764.678 us; speedup 1.0000x reference)
//
#include <hip/hip_runtime.h>
#include <math.h>

typedef short  s8v __attribute__((ext_vector_type(8)));   // 8 bf16 (4 VGPRs)
typedef float  f4v __attribute__((ext_vector_type(4)));
typedef unsigned long long ull;

#define S_LEN 512
#define BATCH 64
#define HID   512
#define TPB   256

// ---------------- fast-path workspace layout ----------------
// weights (bf16 hi/lo), then xe bf16, then tagged h records.
// h record = {2 x bf16 (low dword) | tag = tick+1 (high dword)}, 8B.
// Record layout (R3): [slot][rgrp 64][b 64][sub 4] ulls -> the 4 recs of one
// s8v fragment (rgrp = rec>>2) are CONTIGUOUS 32B per (rgrp,b).
// Slot stride unchanged: 16384 ull = 128KB.
#define WI0H_OFF 0L
#define WI0L_OFF 786432L
#define WH0H_OFF 1572864L
#define WH0L_OFF 3145728L
#define WI1H_OFF 4718592L
#define WI1L_OFF 6291456L
#define WH1H_OFF 7864320L
#define WH1L_OFF 9437184L
#define XEB_OFF  11010048L                   // xe bf16 [t*64+b][256]
#define H0R_OFF  27787264L                   // 512 slots x 16384 ull
#define H1R_OFF  94896128L                   // 4 slots x 16384 ull (self-chain lag <= 1)
#define NEED_FAST 95420416L

// ---------------- fallback (fence path, R1) layout ----------------
#define BAR_BYTES   4096
#define HBUF_BYTES  (HID*BATCH*4)
#define A_OFF       BAR_BYTES
#define B_OFF       (A_OFF + 2*HBUF_BYTES)
#define XE_OFF      (B_OFF + 2*HBUF_BYTES)
#define XE_BYTES    ((size_t)S_LEN*64*BATCH*16)

__device__ __forceinline__ float fexp2(float x){ return __builtin_amdgcn_exp2f(x); }
__device__ __forceinline__ float frcp (float x){ return __builtin_amdgcn_rcpf(x); }
__device__ __forceinline__ float sigm (float x){ return frcp(1.f + fexp2(-1.44269504089f*x)); }
__device__ __forceinline__ float tanhx(float x){ return 1.f - 2.f*frcp(1.f + fexp2(2.88539008178f*x)); }
__device__ __forceinline__ float sigmoid_f(float v){ return 1.0f/(1.0f + expf(-v)); }

__device__ __forceinline__ unsigned short f2bf(float f){
  unsigned int u = __float_as_uint(f);
  u = u + 0x7FFFu + ((u >> 16) & 1u);          // RNE
  return (unsigned short)(u >> 16);
}
__device__ __forceinline__ float bf2f(unsigned short s){
  return __uint_as_float(((unsigned int)s) << 16);
}

// =====================================================================
// Phase A kernels
// =====================================================================
__global__ void wcvt_kernel(const float* __restrict__ Wih0, const float* __restrict__ Whh0,
                            const float* __restrict__ Wih1, const float* __restrict__ Whh1,
                            char* __restrict__ ws)
{
  int idx = blockIdx.x * TPB + threadIdx.x;    // 2,752,512 total
  const float* src; long hi_off, lo_off; int pos;
  if (idx < 393216)       { src = Wih0; pos = idx;           hi_off = WI0H_OFF; lo_off = WI0L_OFF; }
  else if (idx < 1179648) { src = Whh0; pos = idx - 393216;  hi_off = WH0H_OFF; lo_off = WH0L_OFF; }
  else if (idx < 1966080) { src = Wih1; pos = idx - 1179648; hi_off = WI1H_OFF; lo_off = WI1L_OFF; }
  else                    { src = Whh1; pos = idx - 1966080; hi_off = WH1H_OFF; lo_off = WH1L_OFF; }
  float w = src[pos];
  unsigned short h = f2bf(w);
  unsigned short l = f2bf(w - bf2f(h));
  ((unsigned short*)(ws + hi_off))[pos] = h;
  ((unsigned short*)(ws + lo_off))[pos] = l;
}

__global__ void gather_xe_bf_kernel(const int* __restrict__ x,
                                    const float* __restrict__ emb,
                                    char* __restrict__ ws)
{
  int idx = blockIdx.x * TPB + threadIdx.x;    // 2,097,152 = 32768 n * 64 k4
  int k4 = idx & 63;
  int n  = idx >> 6;
  int t = n >> 6, b = n & 63;
  int tok = x[b * S_LEN + t];
  float4 v = make_float4(0.f,0.f,0.f,0.f);
  if (tok != 0) v = ((const float4*)emb)[(size_t)tok * 64 + k4];
  unsigned int lo = (unsigned int)f2bf(v.x) | ((unsigned int)f2bf(v.y) << 16);
  unsigned int hi = (unsigned int)f2bf(v.z) | ((unsigned int)f2bf(v.w) << 16);
  ((uint2*)(ws + XEB_OFF))[(long)n * 64 + k4] = make_uint2(lo, hi);
}

// =====================================================================
// Tagged-record primitives. Record = 8B {2xbf16 | tag}. Single-sector 8B
// atomic store => no tearing; tag==want validates the data in the SAME
// 8B word. Poison 0xAAAAAAAA never equals a valid tag (1..512).
//
// R3 consumer protocol: (1) plain cacheable loads (32B contiguous per
// fragment) validated against in-band tags -> L2-shareable among same-XCD
// consumers, MSHR-merged; (2) on ANY tag mismatch (not-yet-visible OR stale
// L2 line) escalate to the sc1 (agent-scope) spin, which bypasses L2 and is
// the correctness anchor.
// =====================================================================
__device__ __forceinline__ void st_rec(ull* p, ull v){
  __hip_atomic_store(p, v, __ATOMIC_RELAXED, __HIP_MEMORY_SCOPE_AGENT);
}

template<int NKS>
__device__ __forceinline__ void load_plain(const ull* __restrict__ sl, int b0, int col,
                                           int quad, int k0s, ull d[2][NKS][4])
{
  #pragma unroll
  for (int ct = 0; ct < 2; ++ct){
    const int b = b0 + ct*16 + col;
    #pragma unroll
    for (int ks = 0; ks < NKS; ++ks){
      const int e = k0s + ks*4 + quad;               // s8v index == rgrp
      const ull* p = sl + (long)e*256 + (long)b*4;   // 32B contiguous
      #pragma unroll
      for (int i = 0; i < 4; ++i) d[ct][ks][i] = p[i];
    }
  }
}

template<int NKS>
__device__ __forceinline__ bool tags_ok(const ull d[2][NKS][4], unsigned want)
{
  bool ok = true;
  #pragma unroll
  for (int ct = 0; ct < 2; ++ct)
    #pragma unroll
    for (int ks = 0; ks < NKS; ++ks)
      #pragma unroll
      for (int i = 0; i < 4; ++i)
        ok = ok && ((unsigned)(d[ct][ks][i] >> 32) == want);
  return __all(ok);
}

template<int NKS>
__device__ __forceinline__ void load_sc1(const ull* __restrict__ sl, int b0, int col,
                                         int quad, int k0s, unsigned want,
                                         ull d[2][NKS][4])
{
  for (;;){
    #pragma unroll
    for (int ct = 0; ct < 2; ++ct){
      const int b = b0 + ct*16 + col;
      #pragma unroll
      for (int ks = 0; ks < NKS; ++ks){
        const int e = k0s + ks*4 + quad;
        const ull* p = sl + (long)e*256 + (long)b*4;
        #pragma unroll
        for (int i = 0; i < 4; ++i)
          d[ct][ks][i] = __hip_atomic_load(p + i, __ATOMIC_RELAXED, __HIP_MEMORY_SCOPE_AGENT);
      }
    }
    if (tags_ok<NKS>(d, want)) break;
    __builtin_amdgcn_s_sleep(1);
  }
}

template<int NKS>
__device__ __forceinline__ void unpack_recs(const ull d[2][NKS][4], s8v bf[2][NKS])
{
  #pragma unroll
  for (int ct = 0; ct < 2; ++ct)
    #pragma unroll
    for (int ks = 0; ks < NKS; ++ks){
      s8v v;
      #pragma unroll
      for (int i = 0; i < 4; ++i){
        unsigned lo = (unsigned)d[ct][ks][i];
        v[2*i]   = (short)(lo & 0xFFFFu);
        v[2*i+1] = (short)(lo >> 16);
      }
      bf[ct][ks] = v;
    }
}

// =====================================================================
// Fused scan body: EVERY wave does a K-slice of BOTH matmuls.
//  - hidden: NKS=4 per wave (4-way K split of K=512), tagged recs, on-chain
//  - input : NKSI per wave (2 for L0 xe K=256, 4 for L1 h0 K=512)
// Software pipeline per tick:
//   issue hidden plain batch (and L1 input plain batch) FIRST ->
//   input phase (validate/escalate + MFMA)  [hidden loads in flight] ->
//   validate hidden (usually arrived during input compute) -> hidden MFMA.
// =====================================================================
template<int NKSI, int TAGIN>
__device__ __forceinline__ void scan_fused(
    int rowWG, int wave, int lane, int j0, int b0,
    const s8v* __restrict__ WHhi, const s8v* __restrict__ WHlo,
    const s8v* __restrict__ WIhi, const s8v* __restrict__ WIlo,
    const s8v* __restrict__ xsrc,
    const ull* __restrict__ rin,  int inSlotMask,
    const ull* __restrict__ rhid, int hidSlotMask,
    const float* __restrict__ bih, const float* __restrict__ bhh,
    ull* __restrict__ rout, int outMask,
    f4v* __restrict__ part)
{
  const int quad = lane >> 4, col = lane & 15;
  const int k0h  = wave * 16;            // hidden s8v base (NKS=4 -> 16 s8v span)
  const int k0i  = wave * (NKSI * 4);    // input  s8v base
  const int AKsI = TAGIN ? 64 : 32;      // input weight row stride in s8v

  // ---- resident weight fragments (hi + lo) ----
  s8v hh[3][4], hl[3][4], ih[3][NKSI], il[3][NKSI];
  #pragma unroll
  for (int g = 0; g < 3; ++g){
    const int row = g*512 + j0 + col;
    #pragma unroll
    for (int ks = 0; ks < 4; ++ks){
      const int e = row*64 + k0h + ks*4 + quad;
      hh[g][ks] = WHhi[e]; hl[g][ks] = WHlo[e];
    }
    #pragma unroll
    for (int ks = 0; ks < NKSI; ++ks){
      const int e = row*AKsI + k0i + ks*4 + quad;
      ih[g][ks] = WIhi[e]; il[g][ks] = WIlo[e];
    }
  }

  // ---- per-thread gate constants + persistent fp32 h (lane<32) ----
  float cr[4], cz[4], cnx[4], cnh[4], hp[4];
  #pragma unroll
  for (int r4 = 0; r4 < 4; ++r4){
    int j = j0 + wave*4 + r4;
    cr[r4]  = bih[j]      + bhh[j];
    cz[r4]  = bih[512+j]  + bhh[512+j];
    cnx[r4] = bih[1024+j];
    cnh[r4] = bhh[1024+j];
    hp[r4]  = 0.f;
  }

  for (int t = 0; t < S_LEN; ++t){
    f4v aR[2], aZ[2], aNX[2], aNH[2];
    #pragma unroll
    for (int ct = 0; ct < 2; ++ct){
      aR[ct] = (f4v)0.f; aZ[ct] = (f4v)0.f; aNX[ct] = (f4v)0.f; aNH[ct] = (f4v)0.f;
    }

    // ---------- EARLY ISSUE: hidden plain batch (in flight across input) ----
    const ull* slh = rhid + (long)((t-1) & hidSlotMask)*16384;
    const unsigned wanth = (unsigned)t;
    ull hd[2][4][4];
    if (t > 0) load_plain<4>(slh, b0, col, quad, k0h, hd);

    // ---------- input phase (off the recurrence chain) ----------
    if (TAGIN == 0){
      #pragma unroll
      for (int ct = 0; ct < 2; ++ct){
        const int nG = b0 + ct*16 + col;
        const long base = ((long)t*64 + nG)*32 + k0i + quad;   // xe: 32 s8v per row
        #pragma unroll
        for (int ks = 0; ks < NKSI; ++ks){
          s8v bf = xsrc[base + ks*4];
          aR[ct]  = __builtin_amdgcn_mfma_f32_16x16x32_bf16(ih[0][ks], bf, aR[ct], 0, 0, 0);
          aR[ct]  = __builtin_amdgcn_mfma_f32_16x16x32_bf16(il[0][ks], bf, aR[ct], 0, 0, 0);
          aZ[ct]  = __builtin_amdgcn_mfma_f32_16x16x32_bf16(ih[1][ks], bf, aZ[ct], 0, 0, 0);
          aZ[ct]  = __builtin_amdgcn_mfma_f32_16x16x32_bf16(il[1][ks], bf, aZ[ct], 0, 0, 0);
          aNX[ct] = __builtin_amdgcn_mfma_f32_16x16x32_bf16(ih[2][ks], bf, aNX[ct], 0, 0, 0);
          aNX[ct] = __builtin_amdgcn_mfma_f32_16x16x32_bf16(il[2][ks], bf, aNX[ct], 0, 0, 0);
        }
      }
    } else {
      const ull* sli = rin + (long)(t & inSlotMask)*16384;
      const unsigned wanti = (unsigned)(t+1);
      ull idt[2][NKSI][4];
      load_plain<NKSI>(sli, b0, col, quad, k0i, idt);
      if (!tags_ok<NKSI>(idt, wanti))
        load_sc1<NKSI>(sli, b0, col, quad, k0i, wanti, idt);
      s8v bfi[2][NKSI];
      unpack_recs<NKSI>(idt, bfi);
      #pragma unroll
      for (int ct = 0; ct < 2; ++ct)
        #pragma unroll
        for (int ks = 0; ks < NKSI; ++ks){
          aR[ct]  = __builtin_amdgcn_mfma_f32_16x16x32_bf16(ih[0][ks], bfi[ct][ks], aR[ct], 0, 0, 0);
          aR[ct]  = __builtin_amdgcn_mfma_f32_16x16x32_bf16(il[0][ks], bfi[ct][ks], aR[ct], 0, 0, 0);
          aZ[ct]  = __builtin_amdgcn_mfma_f32_16x16x32_bf16(ih[1][ks], bfi[ct][ks], aZ[ct], 0, 0, 0);
          aZ[ct]  = __builtin_amdgcn_mfma_f32_16x16x32_bf16(il[1][ks], bfi[ct][ks], aZ[ct], 0, 0, 0);
          aNX[ct] = __builtin_amdgcn_mfma_f32_16x16x32_bf16(ih[2][ks], bfi[ct][ks], aNX[ct], 0, 0, 0);
          aNX[ct] = __builtin_amdgcn_mfma_f32_16x16x32_bf16(il[2][ks], bfi[ct][ks], aNX[ct], 0, 0, 0);
        }
    }

    // ---------- hidden phase (the chain): validate early batch ----------
    if (t > 0){
      if (!tags_ok<4>(hd, wanth))
        load_sc1<4>(slh, b0, col, quad, k0h, wanth, hd);
      s8v bfh[2][4];
      unpack_recs<4>(hd, bfh);
      #pragma unroll
      for (int ct = 0; ct < 2; ++ct)
        #pragma unroll
        for (int ks = 0; ks < 4; ++ks){
          aR[ct]  = __builtin_amdgcn_mfma_f32_16x16x32_bf16(hh[0][ks], bfh[ct][ks], aR[ct], 0, 0, 0);
          aR[ct]  = __builtin_amdgcn_mfma_f32_16x16x32_bf16(hl[0][ks], bfh[ct][ks], aR[ct], 0, 0, 0);
          aZ[ct]  = __builtin_amdgcn_mfma_f32_16x16x32_bf16(hh[1][ks], bfh[ct][ks], aZ[ct], 0, 0, 0);
          aZ[ct]  = __builtin_amdgcn_mfma_f32_16x16x32_bf16(hl[1][ks], bfh[ct][ks], aZ[ct], 0, 0, 0);
          aNH[ct] = __builtin_amdgcn_mfma_f32_16x16x32_bf16(hh[2][ks], bfh[ct][ks], aNH[ct], 0, 0, 0);
          aNH[ct] = __builtin_amdgcn_mfma_f32_16x16x32_bf16(hl[2][ks], bfh[ct][ks], aNH[ct], 0, 0, 0);
        }
    }

    // ---------- partials to LDS (double-buffered on t&1) ----------
    f4v* pb = part + (t & 1)*2048;
    #pragma unroll
    for (int ct = 0; ct < 2; ++ct){
      pb[((wave*4 + 0)*2 + ct)*64 + lane] = aR[ct];
      pb[((wave*4 + 1)*2 + ct)*64 + lane] = aZ[ct];
      pb[((wave*4 + 2)*2 + ct)*64 + lane] = aNX[ct];
      pb[((wave*4 + 3)*2 + ct)*64 + lane] = aNH[ct];
    }

    // raw barrier: wait only LDS writes, do NOT drain vmcnt (store acks /
    // in-flight loads keep pipelining across the barrier).
    asm volatile("s_waitcnt lgkmcnt(0)" ::: "memory");
    __builtin_amdgcn_s_barrier();
    asm volatile("" ::: "memory");

    // ---- reduce + gate math + tagged h store (wave = row-group, lane<32 = b)
    if (lane < 32){
      const int b = lane;
      const int ct = b >> 4;
      const int pl = wave*16 + (b & 15);
      f4v sr = (f4v)0.f, sz = (f4v)0.f, snx = (f4v)0.f, snh = (f4v)0.f;
      #pragma unroll
      for (int sw = 0; sw < 4; ++sw){
        sr  += pb[((sw*4 + 0)*2 + ct)*64 + pl];
        sz  += pb[((sw*4 + 1)*2 + ct)*64 + pl];
        snx += pb[((sw*4 + 2)*2 + ct)*64 + pl];
        snh += pb[((sw*4 + 3)*2 + ct)*64 + pl];
      }
      const int slotw = t & outMask;
      const ull tg = ((ull)(unsigned)(t + 1)) << 32;
      // rec r = rowWG*8 + wave*2 + pr  ->  rgrp = rowWG*2 + (wave>>1),
      // sub = (wave&1)*2 + pr. Layout: [slot][rgrp][b][sub].
      ull* ob = rout + (long)slotw*16384
                     + (long)(rowWG*2 + (wave>>1))*256
                     + (long)(b0 + b)*4 + (wave&1)*2;
      #pragma unroll
      for (int pr = 0; pr < 2; ++pr){
        unsigned short h2[2];
        #pragma unroll
        for (int q = 0; q < 2; ++q){
          const int r4 = pr*2 + q;
          float r = sigm(sr[r4] + cr[r4]);
          float z = sigm(sz[r4] + cz[r4]);
          float n = tanhx(snx[r4] + cnx[r4] + r*(snh[r4] + cnh[r4]));
          float h = n + z*(hp[r4] - n);
          hp[r4] = h;
          h2[q] = f2bf(h);
        }
        st_rec(ob + pr, ((ull)((unsigned)h2[0] | ((unsigned)h2[1] << 16))) | tg);
      }
    }
  }
}

// =====================================================================
// Persistent MFMA scan kernel: 128 WGs.
// wg 0..63: layer0, wg 64..127: layer1. lw=wg&63: rowWG=lw>>1, bh=lw&1.
// All 4 waves: K-slice of hidden (tagged) + K-slice of input (xe / h0).
// =====================================================================
__global__ __launch_bounds__(TPB, 1) void gru_mfma_kernel(
    const float* __restrict__ bih0, const float* __restrict__ bhh0,
    const float* __restrict__ bih1, const float* __restrict__ bhh1,
    const float* __restrict__ Wfc,  const float* __restrict__ bfc,
    float* __restrict__ out, char* __restrict__ ws)
{
  __shared__ f4v part[2*2048];                 // 64 KB double-buffered partials

  const int tid  = threadIdx.x;
  const int wg   = blockIdx.x;
  const int lane = tid & 63;
  const int wave = tid >> 6;
  const int isL1 = (wg >= 64);
  const int lw   = wg & 63;
  const int rowWG = lw >> 1;
  const int bh    = lw & 1;
  const int j0 = rowWG * 16;
  const int b0 = bh * 32;

  const s8v* wi0h = (const s8v*)(ws + WI0H_OFF); const s8v* wi0l = (const s8v*)(ws + WI0L_OFF);
  const s8v* wh0h = (const s8v*)(ws + WH0H_OFF); const s8v* wh0l = (const s8v*)(ws + WH0L_OFF);
  const s8v* wi1h = (const s8v*)(ws + WI1H_OFF); const s8v* wi1l = (const s8v*)(ws + WI1L_OFF);
  const s8v* wh1h = (const s8v*)(ws + WH1H_OFF); const s8v* wh1l = (const s8v*)(ws + WH1L_OFF);
  const s8v* xeb = (const s8v*)(ws + XEB_OFF);
  const ull* h0r = (const ull*)(ws + H0R_OFF);
  const ull* h1r = (const ull*)(ws + H1R_OFF);
  ull* h0w = (ull*)(ws + H0R_OFF);
  ull* h1w = (ull*)(ws + H1R_OFF);

  if (!isL1){
    scan_fused<2,0>(rowWG, wave, lane, j0, b0,
                    wh0h, wh0l, wi0h, wi0l, xeb,
                    h0r, 0, h0r, 0x3FFFFFFF,
                    bih0, bhh0, h0w, 0x3FFFFFFF, part);
  } else {
    scan_fused<4,1>(rowWG, wave, lane, j0, b0,
                    wh1h, wh1l, wi1h, wi1l, xeb,
                    h0r, 0x3FFFFFFF, h1r, 3,
                    bih1, bhh1, h1w, 3, part);
  }

  // ---- epilogue FC: out[b] = sigmoid(h1_511 . Wfc + bfc), tag-validated ----
  if (wg == 64 && wave == 0){
    const ull* sl = h1r + 3L*16384;            // slot 511 & 3 == 3, tag 512
    float acc = bfc[0];
    for (int c0 = 0; c0 < 256; c0 += 32){
      ull d[32];
      for (;;){
        #pragma unroll
        for (int i = 0; i < 32; ++i){
          const int c = c0 + i;                // rec index
          d[i] = __hip_atomic_load(sl + (long)(c >> 2)*256 + (long)lane*4 + (c & 3),
                                   __ATOMIC_RELAXED, __HIP_MEMORY_SCOPE_AGENT);
        }
        bool ok = true;
        #pragma unroll
        for (int i = 0; i < 32; ++i) ok = ok && ((unsigned)(d[i] >> 32) == 512u);
        if (__all(ok)) break;
        __builtin_amdgcn_s_sleep(1);
      }
      #pragma unroll
      for (int i = 0; i < 32; ++i){
        unsigned lo = (unsigned)d[i];
        int u = (c0 + i) * 2;
        acc += bf2f((unsigned short)(lo & 0xFFFFu)) * Wfc[u]
             + bf2f((unsigned short)(lo >> 16))     * Wfc[u+1];
      }
    }
    out[lane] = sigm(acc);
  }
}

// =====================================================================
// FALLBACK (R1 fence path) — only if ws too small for the fast path.
// =====================================================================
__global__ void gather_xe_kernel(const int* __restrict__ x,
                                 const float* __restrict__ emb,
                                 float4* __restrict__ xe4)
{
  int idx = blockIdx.x * TPB + threadIdx.x;
  int b  = idx & 63;
  int k4 = (idx >> 6) & 63;
  int t  = idx >> 12;
  int tok = x[b * S_LEN + t];
  float4 v = make_float4(0.f, 0.f, 0.f, 0.f);
  if (tok != 0) v = ((const float4*)emb)[(size_t)tok * 64 + k4];
  xe4[idx] = v;
}

__device__ __forceinline__ void accum_vec(const float4* __restrict__ xin,
                                          const float4* __restrict__ w0,
                                          const float4* __restrict__ w1,
                                          const float4* __restrict__ w2,
                                          int n4, int lane,
                                          float& ar, float& az, float& an)
{
  #pragma unroll 4
  for (int k = 0; k < n4; ++k){
    float4 xv = xin[k * 64 + lane];
    float4 wr = w0[k], wz = w1[k], wn = w2[k];
    ar = fmaf(xv.x, wr.x, ar); az = fmaf(xv.x, wz.x, az); an = fmaf(xv.x, wn.x, an);
    ar = fmaf(xv.y, wr.y, ar); az = fmaf(xv.y, wz.y, az); an = fmaf(xv.y, wn.y, an);
    ar = fmaf(xv.z, wr.z, ar); az = fmaf(xv.z, wz.z, az); an = fmaf(xv.z, wn.z, an);
    ar = fmaf(xv.w, wr.w, ar); az = fmaf(xv.w, wz.w, az); an = fmaf(xv.w, wn.w, an);
  }
}

__device__ __forceinline__ void accum_emb(const int* __restrict__ x,
                                          const float* __restrict__ emb, int t,
                                          const float4* __restrict__ w0,
                                          const float4* __restrict__ w1,
                                          const float4* __restrict__ w2,
                                          int lane, float& ar, float& az, float& an)
{
  int tok = x[lane * S_LEN + t];
  const float4* erow = (const float4*)emb + (size_t)tok * 64;
  float m = (tok != 0) ? 1.0f : 0.0f;
  #pragma unroll 4
  for (int k = 0; k < 64; ++k){
    float4 xv = erow[k];
    float xx = xv.x*m, xy = xv.y*m, xz = xv.z*m, xw = xv.w*m;
    float4 wr = w0[k], wz = w1[k], wn = w2[k];
    ar = fmaf(xx, wr.x, ar); az = fmaf(xx, wz.x, az); an = fmaf(xx, wn.x, an);
    ar = fmaf(xy, wr.y, ar); az = fmaf(xy, wz.y, az); an = fmaf(xy, wn.y, an);
    ar = fmaf(xz, wr.z, ar); az = fmaf(xz, wz.z, az); an = fmaf(xz, wn.z, an);
    ar = fmaf(xw, wr.w, ar); az = fmaf(xw, wz.w, az); an = fmaf(xw, wn.w, an);
  }
}

__device__ __forceinline__ void stage_weights(float4* wlds, int tid, int j0, int kin4,
                                              const float* Wih, const float* Whh)
{
  const int per = 3 * (kin4 + 128);
  for (int idx = tid; idx < 4 * per; idx += TPB){
    int w = idx / per, rem = idx - w * per;
    int g = rem / (kin4 + 128), k = rem - g * (kin4 + 128);
    int row = g * HID + j0 + w;
    float4 v;
    if (k < kin4) v = ((const float4*)Wih)[(size_t)row * kin4 + k];
    else          v = ((const float4*)Whh)[(size_t)row * 128 + (k - kin4)];
    wlds[(w * 3 + g) * 256 + k] = v;
  }
}

__device__ __forceinline__ void barrier_tick(int* bar, int wg, int tid, int phase)
{
  __syncthreads();
  if (tid == 0){
    __builtin_amdgcn_fence(__ATOMIC_RELEASE, "agent");
    int* leaf = bar + 32 + (wg >> 4) * 32;
    int old = __hip_atomic_fetch_add(leaf, 1, __ATOMIC_ACQ_REL, __HIP_MEMORY_SCOPE_AGENT);
    if (old == phase * 16 + 15){
      __hip_atomic_fetch_add(bar, 1, __ATOMIC_ACQ_REL, __HIP_MEMORY_SCOPE_AGENT);
    }
    const int target = (phase + 1) * 16;
    while (__hip_atomic_load(bar, __ATOMIC_ACQUIRE, __HIP_MEMORY_SCOPE_AGENT) < target){
      __builtin_amdgcn_s_sleep(2);
    }
    __builtin_amdgcn_fence(__ATOMIC_ACQUIRE, "agent");
  }
  __syncthreads();
}

__device__ __forceinline__ void finish_store(const float4* __restrict__ hprev,
                                             float ar, float az, float anx, float anh,
                                             int lane, int j, float4* __restrict__ hout)
{
  float r  = sigmoid_f(ar);
  float zz = sigmoid_f(az);
  float n  = tanhf(fmaf(r, anh, anx));
  int fi = ((j >> 2) * 64 + lane) * 4 + (j & 3);
  float hhp = ((const float*)hprev)[fi];
  ((float*)hout)[fi] = fmaf(zz, hhp - n, n);
}

__global__ __launch_bounds__(TPB) void gru_persist_kernel(
    const int*   __restrict__ x,    const float* __restrict__ emb,
    const float* __restrict__ Wih0, const float* __restrict__ Whh0,
    const float* __restrict__ bih0, const float* __restrict__ bhh0,
    const float* __restrict__ Wih1, const float* __restrict__ Whh1,
    const float* __restrict__ bih1, const float* __restrict__ bhh1,
    const float* __restrict__ Wfc,  const float* __restrict__ bfc,
    float* __restrict__ out, int* __restrict__ bar,
    float4* __restrict__ A0, float4* __restrict__ A1,
    float4* __restrict__ B0, float4* __restrict__ B1,
    const float4* __restrict__ xe4, int use_xe)
{
  __shared__ float4 wlds[3072];
  const int tid  = threadIdx.x;
  const int wg   = blockIdx.x;
  const int lane = tid & 63;
  const int wave = tid >> 6;
  const bool isL1 = (wg >= 128);
  const int j0   = (isL1 ? wg - 128 : wg) * 4;
  const int kin4 = isL1 ? 128 : 64;

  stage_weights(wlds, tid, j0, kin4, isL1 ? Wih1 : Wih0, isL1 ? Whh1 : Whh0);
  __syncthreads();

  const int j = j0 + wave;
  const float* bih = isL1 ? bih1 : bih0;
  const float* bhh = isL1 ? bhh1 : bhh0;
  const float br  = bih[j]        + bhh[j];
  const float bz  = bih[j + 512]  + bhh[j + 512];
  const float bnx = bih[j + 1024];
  const float bnh = bhh[j + 1024];

  const float4* w0 = &wlds[(wave * 3 + 0) * 256];
  const float4* w1 = &wlds[(wave * 3 + 1) * 256];
  const float4* w2 = &wlds[(wave * 3 + 2) * 256];

  float4* A[2] = {A0, A1};
  float4* B[2] = {B0, B1};

  for (int t = 0; t <= S_LEN; ++t){
    if (!isL1){
      if (t < S_LEN){
        const float4* hprev = A[(t + 1) & 1];
        float ar = br, az = bz, anx = bnx, anh = bnh;
        if (use_xe) accum_vec(xe4 + (size_t)t * 4096, w0, w1, w2, 64, lane, ar, az, anx);
        else        accum_emb(x, emb, t, w0, w1, w2, lane, ar, az, anx);
        accum_vec(hprev, w0 + 64, w1 + 64, w2 + 64, 128, lane, ar, az, anh);
        finish_store(hprev, ar, az, anx, anh, lane, j, A[t & 1]);
      }
    } else if (t >= 1){
      const int u = t - 1;
      const float4* xin   = A[u & 1];
      const float4* hprev = B[(u + 1) & 1];
      float ar = br, az = bz, anx = bnx, anh = bnh;
      accum_vec(xin,   w0,       w1,       w2,       128, lane, ar, az, anx);
      accum_vec(hprev, w0 + 128, w1 + 128, w2 + 128, 128, lane, ar, az, anh);
      finish_store(hprev, ar, az, anx, anh, lane, j, B[u & 1]);
    }
    barrier_tick(bar, wg, tid, t);
  }

  if (wg == 0 && wave == 0){
    float acc = bfc[0];
    const float4* h1 = B[1];
    const float4* wf = (const float4*)Wfc;
    #pragma unroll 4
    for (int k = 0; k < 128; ++k){
      float4 hv = h1[k * 64 + lane];
      float4 wv = wf[k];
      acc = fmaf(hv.x, wv.x, acc); acc = fmaf(hv.y, wv.y, acc);
      acc = fmaf(hv.z, wv.z, acc); acc = fmaf(hv.w, wv.w, acc);
    }
    out[lane] = sigmoid_f(acc);
  }
}

extern "C" void kernel_launch(void* const* d_in, const int* in_sizes, int n_in,
                              void* d_out, int out_size, void* d_ws, size_t ws_size,
                              hipStream_t stream)
{
  (void)in_sizes; (void)n_in; (void)out_size;
  const int*   x    = (const int*)  d_in[0];
  const float* emb  = (const float*)d_in[1];
  const float* Wih0 = (const float*)d_in[2];
  const float* Whh0 = (const float*)d_in[3];
  const float* bih0 = (const float*)d_in[4];
  const float* bhh0 = (const float*)d_in[5];
  const float* Wih1 = (const float*)d_in[6];
  const float* Whh1 = (const float*)d_in[7];
  const float* bih1 = (const float*)d_in[8];
  const float* bhh1 = (const float*)d_in[9];
  const float* Wfc  = (const float*)d_in[10];
  const float* bfc  = (const float*)d_in[11];
  float* out = (float*)d_out;
  char* ws = (char*)d_ws;

  if (ws_size >= (size_t)NEED_FAST){
    // no sync memset needed: tagged records self-validate against 0xAA poison
    wcvt_kernel<<<2752512 / TPB, TPB, 0, stream>>>(Wih0, Whh0, Wih1, Whh1, ws);
    gather_xe_bf_kernel<<<2097152 / TPB, TPB, 0, stream>>>(x, emb, ws);
    gru_mfma_kernel<<<128, TPB, 0, stream>>>(bih0, bhh0, bih1, bhh1, Wfc, bfc, out, ws);
  } else {
    int*    bar = (int*)ws;
    float4* A0  = (float4*)(ws + A_OFF);
    float4* A1  = (float4*)(ws + A_OFF + HBUF_BYTES);
    float4* B0  = (float4*)(ws + B_OFF);
    float4* B1  = (float4*)(ws + B_OFF + HBUF_BYTES);
    float4* xe4 = (float4*)(ws + XE_OFF);
    const int use_xe = (ws_size >= (size_t)XE_OFF + XE_BYTES) ? 1 : 0;
    hipMemsetAsync(ws, 0, XE_OFF, stream);
    if (use_xe){
      gather_xe_kernel<<<(S_LEN * 64 * BATCH) / TPB, TPB, 0, stream>>>(x, emb, xe4);
    }
    gru_persist_kernel<<<256, TPB, 0, stream>>>(
        x, emb, Wih0, Whh0, bih0, bhh0, Wih1, Whh1, bih1, bhh1, Wfc, bfc,
        out, bar, A0, A1, B0, B1, xe4, use_xe);
  }
}

// Round 5
// 2061.205 us; speedup vs baseline: 1.3413x; 1.3413x over previous
//
#include <hip/hip_runtime.h>
#include <math.h>

typedef short  s8v __attribute__((ext_vector_type(8)));   // 8 bf16 (4 VGPRs)
typedef float  f4v __attribute__((ext_vector_type(4)));
typedef unsigned long long ull;

#define S_LEN 512
#define BATCH 64
#define HID   512
#define TPB   256

// ---------------- fast-path workspace layout ----------------
// weights (bf16 hi/lo), then xe bf16, then tagged h records.
// h record = {2 x bf16 (low dword) | tag = tick+1 (high dword)}, 8B, layout [slot][rec 256][b 64]
#define WI0H_OFF 0L
#define WI0L_OFF 786432L
#define WH0H_OFF 1572864L
#define WH0L_OFF 3145728L
#define WI1H_OFF 4718592L
#define WI1L_OFF 6291456L
#define WH1H_OFF 7864320L
#define WH1L_OFF 9437184L
#define XEB_OFF  11010048L                   // xe bf16 [t*64+b][256]
#define H0R_OFF  27787264L                   // 512 slots x 16384 ull
#define H1R_OFF  94896128L                   // 4 slots x 16384 ull (self-chain lag <= 1)
#define NEED_FAST 95420416L

// ---------------- fallback (fence path, R1) layout ----------------
#define BAR_BYTES   4096
#define HBUF_BYTES  (HID*BATCH*4)
#define A_OFF       BAR_BYTES
#define B_OFF       (A_OFF + 2*HBUF_BYTES)
#define XE_OFF      (B_OFF + 2*HBUF_BYTES)
#define XE_BYTES    ((size_t)S_LEN*64*BATCH*16)

__device__ __forceinline__ float fexp2(float x){ return __builtin_amdgcn_exp2f(x); }
__device__ __forceinline__ float frcp (float x){ return __builtin_amdgcn_rcpf(x); }
__device__ __forceinline__ float sigm (float x){ return frcp(1.f + fexp2(-1.44269504089f*x)); }
__device__ __forceinline__ float tanhx(float x){ return 1.f - 2.f*frcp(1.f + fexp2(2.88539008178f*x)); }
__device__ __forceinline__ float sigmoid_f(float v){ return 1.0f/(1.0f + expf(-v)); }

__device__ __forceinline__ unsigned short f2bf(float f){
  unsigned int u = __float_as_uint(f);
  u = u + 0x7FFFu + ((u >> 16) & 1u);          // RNE
  return (unsigned short)(u >> 16);
}
__device__ __forceinline__ float bf2f(unsigned short s){
  return __uint_as_float(((unsigned int)s) << 16);
}

// =====================================================================
// Phase A kernels
// =====================================================================
__global__ void wcvt_kernel(const float* __restrict__ Wih0, const float* __restrict__ Whh0,
                            const float* __restrict__ Wih1, const float* __restrict__ Whh1,
                            char* __restrict__ ws)
{
  int idx = blockIdx.x * TPB + threadIdx.x;    // 2,752,512 total
  const float* src; long hi_off, lo_off; int pos;
  if (idx < 393216)       { src = Wih0; pos = idx;           hi_off = WI0H_OFF; lo_off = WI0L_OFF; }
  else if (idx < 1179648) { src = Whh0; pos = idx - 393216;  hi_off = WH0H_OFF; lo_off = WH0L_OFF; }
  else if (idx < 1966080) { src = Wih1; pos = idx - 1179648; hi_off = WI1H_OFF; lo_off = WI1L_OFF; }
  else                    { src = Whh1; pos = idx - 1966080; hi_off = WH1H_OFF; lo_off = WH1L_OFF; }
  float w = src[pos];
  unsigned short h = f2bf(w);
  unsigned short l = f2bf(w - bf2f(h));
  ((unsigned short*)(ws + hi_off))[pos] = h;
  ((unsigned short*)(ws + lo_off))[pos] = l;
}

__global__ void gather_xe_bf_kernel(const int* __restrict__ x,
                                    const float* __restrict__ emb,
                                    char* __restrict__ ws)
{
  int idx = blockIdx.x * TPB + threadIdx.x;    // 2,097,152 = 32768 n * 64 k4
  int k4 = idx & 63;
  int n  = idx >> 6;
  int t = n >> 6, b = n & 63;
  int tok = x[b * S_LEN + t];
  float4 v = make_float4(0.f,0.f,0.f,0.f);
  if (tok != 0) v = ((const float4*)emb)[(size_t)tok * 64 + k4];
  unsigned int lo = (unsigned int)f2bf(v.x) | ((unsigned int)f2bf(v.y) << 16);
  unsigned int hi = (unsigned int)f2bf(v.z) | ((unsigned int)f2bf(v.w) << 16);
  ((uint2*)(ws + XEB_OFF))[(long)n * 64 + k4] = make_uint2(lo, hi);
}

// =====================================================================
// Tagged-record primitives. Record = 8B {2xbf16 | tag}. Single-sector 8B
// atomic load/store => no tearing; tag==want validates the data in the SAME
// transaction. Poison 0xAAAAAAAA never equals a valid tag (1..512).
// =====================================================================
__device__ __forceinline__ void st_rec(ull* p, ull v){
  __hip_atomic_store(p, v, __ATOMIC_RELAXED, __HIP_MEMORY_SCOPE_AGENT);
}

// fetch+validate one ct-halve of B fragments (NKS s8v) for this lane.
template<int NKS>
__device__ __forceinline__ void load_ct(const ull* __restrict__ sl, int b,
                                        int quad, int k0s, unsigned want,
                                        s8v* __restrict__ bf)
{
  ull d[NKS][4];
  for (;;){
    #pragma unroll
    for (int ks = 0; ks < NKS; ++ks){
      const int e = k0s + ks*4 + quad;             // s8v index -> units [8e,8e+8)
      const ull* p = sl + (long)(4*e)*64 + b;      // recs 4e..4e+3, [rec][b]
      #pragma unroll
      for (int i = 0; i < 4; ++i)
        d[ks][i] = __hip_atomic_load(p + (long)i*64, __ATOMIC_RELAXED, __HIP_MEMORY_SCOPE_AGENT);
    }
    bool ok = true;
    #pragma unroll
    for (int ks = 0; ks < NKS; ++ks)
      #pragma unroll
      for (int i = 0; i < 4; ++i)
        ok = ok && ((unsigned)(d[ks][i] >> 32) == want);
    if (__all(ok)) break;
    __builtin_amdgcn_s_sleep(1);
  }
  #pragma unroll
  for (int ks = 0; ks < NKS; ++ks){
    s8v v;
    #pragma unroll
    for (int i = 0; i < 4; ++i){
      unsigned lo = (unsigned)d[ks][i];
      v[2*i]   = (short)(lo & 0xFFFFu);
      v[2*i+1] = (short)(lo >> 16);
    }
    bf[ks] = v;
  }
}

// R5: non-blocking issue of one ct-halve (no spin) — used to hide the ct1
// round-trip under the ct0 MFMA block. Same addresses/protocol as load_ct.
template<int NKS>
__device__ __forceinline__ void issue_ct(const ull* __restrict__ sl, int b,
                                         int quad, int k0s, ull d[NKS][4])
{
  #pragma unroll
  for (int ks = 0; ks < NKS; ++ks){
    const int e = k0s + ks*4 + quad;
    const ull* p = sl + (long)(4*e)*64 + b;
    #pragma unroll
    for (int i = 0; i < 4; ++i)
      d[ks][i] = __hip_atomic_load(p + (long)i*64, __ATOMIC_RELAXED, __HIP_MEMORY_SCOPE_AGENT);
  }
}

template<int NKS>
__device__ __forceinline__ bool ctags_ok(const ull d[NKS][4], unsigned want)
{
  bool ok = true;
  #pragma unroll
  for (int ks = 0; ks < NKS; ++ks)
    #pragma unroll
    for (int i = 0; i < 4; ++i)
      ok = ok && ((unsigned)(d[ks][i] >> 32) == want);
  return __all(ok);
}

template<int NKS>
__device__ __forceinline__ void unpack_ct(const ull d[NKS][4], s8v* __restrict__ bf)
{
  #pragma unroll
  for (int ks = 0; ks < NKS; ++ks){
    s8v v;
    #pragma unroll
    for (int i = 0; i < 4; ++i){
      unsigned lo = (unsigned)d[ks][i];
      v[2*i]   = (short)(lo & 0xFFFFu);
      v[2*i+1] = (short)(lo >> 16);
    }
    bf[ks] = v;
  }
}

// =====================================================================
// scan body: one wave's role for the whole 512-tick loop.
// ROLE: 0 = xe input (plain loads), 1 = self-layer hidden (tagged, slot (t-1)&mask,
//       want t), 2 = cross h0 input (tagged, slot t, want t+1)
//
// R5 change (the ONLY change vs the proven R0 structure): for tagged roles,
// after the ct0 spin succeeds, ct1 is guaranteed-published (the producer's
// two st_rec instructions cover BOTH ct halves: lanes 0..31 = batches
// b0..b0+31). So: spin ct0 -> issue ct1 loads -> MFMA ct0 (ct1 round-trip
// hides underneath) -> validate ct1 once (fallback: original spin) -> MFMA ct1.
// =====================================================================
template<int NKS, int ROLE>
__device__ __forceinline__ void scan_body(
    int isL1, int rowWG, int bh, int wave, int lane, int tid, int j0, int b0,
    const s8v* __restrict__ Whi, const s8v* __restrict__ Wlo, int AKs, int k0s,
    const s8v* __restrict__ xsrc,
    const ull* __restrict__ rsrc, int slotMask,
    const float* __restrict__ bih, const float* __restrict__ bhh,
    ull* __restrict__ rout, int outMask,
    f4v* __restrict__ part)
{
  const int quad = lane >> 4, col = lane & 15;

  // ---- A fragments (hi + lo), resident across all 512 ticks ----
  s8v ahi[3][NKS], alo[3][NKS];
  #pragma unroll
  for (int rt = 0; rt < 3; ++rt){
    const int row = rt*512 + j0 + col;
    #pragma unroll
    for (int ks = 0; ks < NKS; ++ks){
      const int e = row*AKs + k0s + ks*4 + quad;
      ahi[rt][ks] = Whi[e];
      alo[rt][ks] = Wlo[e];
    }
  }

  // ---- per-thread gate constants + persistent fp32 h (lane<32) ----
  float cr[4], cz[4], cnx[4], cnh[4], hp[4];
  #pragma unroll
  for (int r4 = 0; r4 < 4; ++r4){
    int j = j0 + wave*4 + r4;
    cr[r4]  = bih[j]      + bhh[j];
    cz[r4]  = bih[512+j]  + bhh[512+j];
    cnx[r4] = bih[1024+j];
    cnh[r4] = bhh[1024+j];
    hp[r4]  = 0.f;
  }

  for (int t = 0; t < S_LEN; ++t){
    f4v acc[3][2];
    #pragma unroll
    for (int rt = 0; rt < 3; ++rt){ acc[rt][0] = (f4v)0.f; acc[rt][1] = (f4v)0.f; }

    const bool active = (ROLE != 1) || (t > 0);
    if (active){
      if (ROLE == 0){
        #pragma unroll
        for (int ct = 0; ct < 2; ++ct){
          const int nG = b0 + ct*16 + col;
          const long base = ((long)t*64 + nG)*32 + k0s + quad;   // xe: 32 s8v per row
          #pragma unroll
          for (int ks = 0; ks < NKS; ++ks){
            s8v bf = xsrc[base + ks*4];
            #pragma unroll
            for (int rt = 0; rt < 3; ++rt){
              acc[rt][ct] = __builtin_amdgcn_mfma_f32_16x16x32_bf16(ahi[rt][ks], bf, acc[rt][ct], 0, 0, 0);
              acc[rt][ct] = __builtin_amdgcn_mfma_f32_16x16x32_bf16(alo[rt][ks], bf, acc[rt][ct], 0, 0, 0);
            }
          }
        }
      } else {
        const ull* sl = (ROLE == 1) ? rsrc + (long)((t-1) & slotMask)*16384
                                    : rsrc + (long)(t & slotMask)*16384;
        const unsigned want = (ROLE == 1) ? (unsigned)t : (unsigned)(t+1);

        // ---- ct0: blocking spin (the rendezvous) ----
        s8v bf0[NKS];
        load_ct<NKS>(sl, b0 + col, quad, k0s, want, bf0);

        // ---- ct1: issue now; round-trip hides under ct0 MFMAs ----
        ull d1[NKS][4];
        issue_ct<NKS>(sl, b0 + 16 + col, quad, k0s, d1);

        // ---- ct0 MFMAs ----
        #pragma unroll
        for (int ks = 0; ks < NKS; ++ks)
          #pragma unroll
          for (int rt = 0; rt < 3; ++rt){
            acc[rt][0] = __builtin_amdgcn_mfma_f32_16x16x32_bf16(ahi[rt][ks], bf0[ks], acc[rt][0], 0, 0, 0);
            acc[rt][0] = __builtin_amdgcn_mfma_f32_16x16x32_bf16(alo[rt][ks], bf0[ks], acc[rt][0], 0, 0, 0);
          }

        // ---- ct1: validate once (expected hit), else original spin ----
        s8v bf1[NKS];
        if (ctags_ok<NKS>(d1, want)) unpack_ct<NKS>(d1, bf1);
        else load_ct<NKS>(sl, b0 + 16 + col, quad, k0s, want, bf1);

        // ---- ct1 MFMAs ----
        #pragma unroll
        for (int ks = 0; ks < NKS; ++ks)
          #pragma unroll
          for (int rt = 0; rt < 3; ++rt){
            acc[rt][1] = __builtin_amdgcn_mfma_f32_16x16x32_bf16(ahi[rt][ks], bf1[ks], acc[rt][1], 0, 0, 0);
            acc[rt][1] = __builtin_amdgcn_mfma_f32_16x16x32_bf16(alo[rt][ks], bf1[ks], acc[rt][1], 0, 0, 0);
          }
      }
    }

    // ---- partials to LDS ----
    #pragma unroll
    for (int rt = 0; rt < 3; ++rt)
      #pragma unroll
      for (int ct = 0; ct < 2; ++ct)
        part[(wave*6 + rt*2 + ct)*64 + lane] = acc[rt][ct];
    __syncthreads();

    // ---- reduce + gate math + tagged h store (wave = unit-group, lane<32 = b)
    if (lane < 32){
      const int b = lane;
      const int pl = wave*16 + (b & 15);
      const int ct = b >> 4;
      f4v sr = (f4v)0.f, sz = (f4v)0.f, snx = (f4v)0.f, snh = (f4v)0.f;
      #pragma unroll
      for (int w = 0; w < 4; ++w){
        const bool inpW = isL1 ? (w < 2) : (w >= 2);
        f4v g0 = part[(w*6 + 0*2 + ct)*64 + pl];
        f4v g1 = part[(w*6 + 1*2 + ct)*64 + pl];
        f4v g2 = part[(w*6 + 2*2 + ct)*64 + pl];
        sr += g0; sz += g1;
        if (inpW) snx += g2; else snh += g2;
      }
      unsigned short hb[4];
      #pragma unroll
      for (int r4 = 0; r4 < 4; ++r4){
        float r = sigm(sr[r4] + cr[r4]);
        float z = sigm(sz[r4] + cz[r4]);
        float n = tanhx(snx[r4] + cnx[r4] + r*(snh[r4] + cnh[r4]));
        float h = n + z*(hp[r4] - n);
        hp[r4] = h;
        hb[r4] = f2bf(h);
      }
      const int slotw = t & outMask;
      const ull tg = ((ull)(unsigned)(t + 1)) << 32;
      ull* ob = rout + (long)slotw*16384 + (long)(rowWG*8 + wave*2)*64 + (b0 + b);
      st_rec(ob,      ((ull)((unsigned)hb[0] | ((unsigned)hb[1] << 16))) | tg);
      st_rec(ob + 64, ((ull)((unsigned)hb[2] | ((unsigned)hb[3] << 16))) | tg);
    }
    __syncthreads();                         // partial buffer reuse next tick
  }
}

// =====================================================================
// Persistent MFMA scan kernel: 128 WGs.
// wg 0..63: layer0, wg 64..127: layer1. lw=wg&63: rowWG=lw>>1, bh=lw&1.
// L0: waves 0-1 hidden (h0 tagged), waves 2-3 xe input (plain).
// L1: waves 0-1 input (h0 tagged, cross), waves 2-3 hidden (h1 tagged, 4-slot ring).
// =====================================================================
__global__ __launch_bounds__(TPB, 1) void gru_mfma_kernel(
    const float* __restrict__ bih0, const float* __restrict__ bhh0,
    const float* __restrict__ bih1, const float* __restrict__ bhh1,
    const float* __restrict__ Wfc,  const float* __restrict__ bfc,
    float* __restrict__ out, char* __restrict__ ws)
{
  __shared__ f4v part[4*6*64];                 // 24 KB partial-reduce buffer

  const int tid  = threadIdx.x;
  const int wg   = blockIdx.x;
  const int lane = tid & 63;
  const int wave = tid >> 6;
  const int isL1 = (wg >= 64);
  const int lw   = wg & 63;
  const int rowWG = lw >> 1;
  const int bh    = lw & 1;
  const int j0 = rowWG * 16;
  const int b0 = bh * 32;

  const s8v* wi0h = (const s8v*)(ws + WI0H_OFF); const s8v* wi0l = (const s8v*)(ws + WI0L_OFF);
  const s8v* wh0h = (const s8v*)(ws + WH0H_OFF); const s8v* wh0l = (const s8v*)(ws + WH0L_OFF);
  const s8v* wi1h = (const s8v*)(ws + WI1H_OFF); const s8v* wi1l = (const s8v*)(ws + WI1L_OFF);
  const s8v* wh1h = (const s8v*)(ws + WH1H_OFF); const s8v* wh1l = (const s8v*)(ws + WH1L_OFF);
  const s8v* xeb = (const s8v*)(ws + XEB_OFF);
  const ull* h0r = (const ull*)(ws + H0R_OFF);
  const ull* h1r = (const ull*)(ws + H1R_OFF);
  ull* h0w = (ull*)(ws + H0R_OFF);
  ull* h1w = (ull*)(ws + H1R_OFF);

  if (!isL1){
    if (wave < 2)
      scan_body<8,1>(isL1, rowWG, bh, wave, lane, tid, j0, b0,
                     wh0h, wh0l, 64, wave*32, xeb, h0r, 0x3FFFFFFF,
                     bih0, bhh0, h0w, 0x3FFFFFFF, part);
    else
      scan_body<4,0>(isL1, rowWG, bh, wave, lane, tid, j0, b0,
                     wi0h, wi0l, 32, (wave-2)*16, xeb, h0r, 0x3FFFFFFF,
                     bih0, bhh0, h0w, 0x3FFFFFFF, part);
  } else {
    if (wave < 2)
      scan_body<8,2>(isL1, rowWG, bh, wave, lane, tid, j0, b0,
                     wi1h, wi1l, 64, wave*32, xeb, h0r, 0x3FFFFFFF,
                     bih1, bhh1, h1w, 3, part);
    else
      scan_body<8,1>(isL1, rowWG, bh, wave, lane, tid, j0, b0,
                     wh1h, wh1l, 64, (wave-2)*32, xeb, h1r, 3,
                     bih1, bhh1, h1w, 3, part);
  }

  // ---- epilogue FC: out[b] = sigmoid(h1_511 . Wfc + bfc), tag-validated ----
  if (wg == 64 && wave == 0){
    const ull* sl = h1r + 3L*16384;            // slot 511 & 3 == 3, tag 512
    float acc = bfc[0];
    for (int c0 = 0; c0 < 256; c0 += 32){
      ull d[32];
      for (;;){
        #pragma unroll
        for (int i = 0; i < 32; ++i)
          d[i] = __hip_atomic_load(sl + (long)(c0+i)*64 + lane,
                                   __ATOMIC_RELAXED, __HIP_MEMORY_SCOPE_AGENT);
        bool ok = true;
        #pragma unroll
        for (int i = 0; i < 32; ++i) ok = ok && ((unsigned)(d[i] >> 32) == 512u);
        if (__all(ok)) break;
        __builtin_amdgcn_s_sleep(1);
      }
      #pragma unroll
      for (int i = 0; i < 32; ++i){
        unsigned lo = (unsigned)d[i];
        int u = (c0 + i) * 2;
        acc += bf2f((unsigned short)(lo & 0xFFFFu)) * Wfc[u]
             + bf2f((unsigned short)(lo >> 16))     * Wfc[u+1];
      }
    }
    out[lane] = sigm(acc);
  }
}

// =====================================================================
// FALLBACK (R1 fence path) — only if ws too small for the fast path.
// =====================================================================
__global__ void gather_xe_kernel(const int* __restrict__ x,
                                 const float* __restrict__ emb,
                                 float4* __restrict__ xe4)
{
  int idx = blockIdx.x * TPB + threadIdx.x;
  int b  = idx & 63;
  int k4 = (idx >> 6) & 63;
  int t  = idx >> 12;
  int tok = x[b * S_LEN + t];
  float4 v = make_float4(0.f, 0.f, 0.f, 0.f);
  if (tok != 0) v = ((const float4*)emb)[(size_t)tok * 64 + k4];
  xe4[idx] = v;
}

__device__ __forceinline__ void accum_vec(const float4* __restrict__ xin,
                                          const float4* __restrict__ w0,
                                          const float4* __restrict__ w1,
                                          const float4* __restrict__ w2,
                                          int n4, int lane,
                                          float& ar, float& az, float& an)
{
  #pragma unroll 4
  for (int k = 0; k < n4; ++k){
    float4 xv = xin[k * 64 + lane];
    float4 wr = w0[k], wz = w1[k], wn = w2[k];
    ar = fmaf(xv.x, wr.x, ar); az = fmaf(xv.x, wz.x, az); an = fmaf(xv.x, wn.x, an);
    ar = fmaf(xv.y, wr.y, ar); az = fmaf(xv.y, wz.y, az); an = fmaf(xv.y, wn.y, an);
    ar = fmaf(xv.z, wr.z, ar); az = fmaf(xv.z, wz.z, az); an = fmaf(xv.z, wn.z, an);
    ar = fmaf(xv.w, wr.w, ar); az = fmaf(xv.w, wz.w, az); an = fmaf(xv.w, wn.w, an);
  }
}

__device__ __forceinline__ void accum_emb(const int* __restrict__ x,
                                          const float* __restrict__ emb, int t,
                                          const float4* __restrict__ w0,
                                          const float4* __restrict__ w1,
                                          const float4* __restrict__ w2,
                                          int lane, float& ar, float& az, float& an)
{
  int tok = x[lane * S_LEN + t];
  const float4* erow = (const float4*)emb + (size_t)tok * 64;
  float m = (tok != 0) ? 1.0f : 0.0f;
  #pragma unroll 4
  for (int k = 0; k < 64; ++k){
    float4 xv = erow[k];
    float xx = xv.x*m, xy = xv.y*m, xz = xv.z*m, xw = xv.w*m;
    float4 wr = w0[k], wz = w1[k], wn = w2[k];
    ar = fmaf(xx, wr.x, ar); az = fmaf(xx, wz.x, az); an = fmaf(xx, wn.x, an);
    ar = fmaf(xy, wr.y, ar); az = fmaf(xy, wz.y, az); an = fmaf(xy, wn.y, an);
    ar = fmaf(xz, wr.z, ar); az = fmaf(xz, wz.z, az); an = fmaf(xz, wn.z, an);
    ar = fmaf(xw, wr.w, ar); az = fmaf(xw, wz.w, az); an = fmaf(xw, wn.w, an);
  }
}

__device__ __forceinline__ void stage_weights(float4* wlds, int tid, int j0, int kin4,
                                              const float* Wih, const float* Whh)
{
  const int per = 3 * (kin4 + 128);
  for (int idx = tid; idx < 4 * per; idx += TPB){
    int w = idx / per, rem = idx - w * per;
    int g = rem / (kin4 + 128), k = rem - g * (kin4 + 128);
    int row = g * HID + j0 + w;
    float4 v;
    if (k < kin4) v = ((const float4*)Wih)[(size_t)row * kin4 + k];
    else          v = ((const float4*)Whh)[(size_t)row * 128 + (k - kin4)];
    wlds[(w * 3 + g) * 256 + k] = v;
  }
}

__device__ __forceinline__ void barrier_tick(int* bar, int wg, int tid, int phase)
{
  __syncthreads();
  if (tid == 0){
    __builtin_amdgcn_fence(__ATOMIC_RELEASE, "agent");
    int* leaf = bar + 32 + (wg >> 4) * 32;
    int old = __hip_atomic_fetch_add(leaf, 1, __ATOMIC_ACQ_REL, __HIP_MEMORY_SCOPE_AGENT);
    if (old == phase * 16 + 15){
      __hip_atomic_fetch_add(bar, 1, __ATOMIC_ACQ_REL, __HIP_MEMORY_SCOPE_AGENT);
    }
    const int target = (phase + 1) * 16;
    while (__hip_atomic_load(bar, __ATOMIC_ACQUIRE, __HIP_MEMORY_SCOPE_AGENT) < target){
      __builtin_amdgcn_s_sleep(2);
    }
    __builtin_amdgcn_fence(__ATOMIC_ACQUIRE, "agent");
  }
  __syncthreads();
}

__device__ __forceinline__ void finish_store(const float4* __restrict__ hprev,
                                             float ar, float az, float anx, float anh,
                                             int lane, int j, float4* __restrict__ hout)
{
  float r  = sigmoid_f(ar);
  float zz = sigmoid_f(az);
  float n  = tanhf(fmaf(r, anh, anx));
  int fi = ((j >> 2) * 64 + lane) * 4 + (j & 3);
  float hhp = ((const float*)hprev)[fi];
  ((float*)hout)[fi] = fmaf(zz, hhp - n, n);
}

__global__ __launch_bounds__(TPB) void gru_persist_kernel(
    const int*   __restrict__ x,    const float* __restrict__ emb,
    const float* __restrict__ Wih0, const float* __restrict__ Whh0,
    const float* __restrict__ bih0, const float* __restrict__ bhh0,
    const float* __restrict__ Wih1, const float* __restrict__ Whh1,
    const float* __restrict__ bih1, const float* __restrict__ bhh1,
    const float* __restrict__ Wfc,  const float* __restrict__ bfc,
    float* __restrict__ out, int* __restrict__ bar,
    float4* __restrict__ A0, float4* __restrict__ A1,
    float4* __restrict__ B0, float4* __restrict__ B1,
    const float4* __restrict__ xe4, int use_xe)
{
  __shared__ float4 wlds[3072];
  const int tid  = threadIdx.x;
  const int wg   = blockIdx.x;
  const int lane = tid & 63;
  const int wave = tid >> 6;
  const bool isL1 = (wg >= 128);
  const int j0   = (isL1 ? wg - 128 : wg) * 4;
  const int kin4 = isL1 ? 128 : 64;

  stage_weights(wlds, tid, j0, kin4, isL1 ? Wih1 : Wih0, isL1 ? Whh1 : Whh0);
  __syncthreads();

  const int j = j0 + wave;
  const float* bih = isL1 ? bih1 : bih0;
  const float* bhh = isL1 ? bhh1 : bhh0;
  const float br  = bih[j]        + bhh[j];
  const float bz  = bih[j + 512]  + bhh[j + 512];
  const float bnx = bih[j + 1024];
  const float bnh = bhh[j + 1024];

  const float4* w0 = &wlds[(wave * 3 + 0) * 256];
  const float4* w1 = &wlds[(wave * 3 + 1) * 256];
  const float4* w2 = &wlds[(wave * 3 + 2) * 256];

  float4* A[2] = {A0, A1};
  float4* B[2] = {B0, B1};

  for (int t = 0; t <= S_LEN; ++t){
    if (!isL1){
      if (t < S_LEN){
        const float4* hprev = A[(t + 1) & 1];
        float ar = br, az = bz, anx = bnx, anh = bnh;
        if (use_xe) accum_vec(xe4 + (size_t)t * 4096, w0, w1, w2, 64, lane, ar, az, anx);
        else        accum_emb(x, emb, t, w0, w1, w2, lane, ar, az, anx);
        accum_vec(hprev, w0 + 64, w1 + 64, w2 + 64, 128, lane, ar, az, anh);
        finish_store(hprev, ar, az, anx, anh, lane, j, A[t & 1]);
      }
    } else if (t >= 1){
      const int u = t - 1;
      const float4* xin   = A[u & 1];
      const float4* hprev = B[(u + 1) & 1];
      float ar = br, az = bz, anx = bnx, anh = bnh;
      accum_vec(xin,   w0,       w1,       w2,       128, lane, ar, az, anx);
      accum_vec(hprev, w0 + 128, w1 + 128, w2 + 128, 128, lane, ar, az, anh);
      finish_store(hprev, ar, az, anx, anh, lane, j, B[u & 1]);
    }
    barrier_tick(bar, wg, tid, t);
  }

  if (wg == 0 && wave == 0){
    float acc = bfc[0];
    const float4* h1 = B[1];
    const float4* wf = (const float4*)Wfc;
    #pragma unroll 4
    for (int k = 0; k < 128; ++k){
      float4 hv = h1[k * 64 + lane];
      float4 wv = wf[k];
      acc = fmaf(hv.x, wv.x, acc); acc = fmaf(hv.y, wv.y, acc);
      acc = fmaf(hv.z, wv.z, acc); acc = fmaf(hv.w, wv.w, acc);
    }
    out[lane] = sigmoid_f(acc);
  }
}

extern "C" void kernel_launch(void* const* d_in, const int* in_sizes, int n_in,
                              void* d_out, int out_size, void* d_ws, size_t ws_size,
                              hipStream_t stream)
{
  (void)in_sizes; (void)n_in; (void)out_size;
  const int*   x    = (const int*)  d_in[0];
  const float* emb  = (const float*)d_in[1];
  const float* Wih0 = (const float*)d_in[2];
  const float* Whh0 = (const float*)d_in[3];
  const float* bih0 = (const float*)d_in[4];
  const float* bhh0 = (const float*)d_in[5];
  const float* Wih1 = (const float*)d_in[6];
  const float* Whh1 = (const float*)d_in[7];
  const float* bih1 = (const float*)d_in[8];
  const float* bhh1 = (const float*)d_in[9];
  const float* Wfc  = (const float*)d_in[10];
  const float* bfc  = (const float*)d_in[11];
  float* out = (float*)d_out;
  char* ws = (char*)d_ws;

  if (ws_size >= (size_t)NEED_FAST){
    // no sync memset needed: tagged records self-validate against 0xAA poison
    wcvt_kernel<<<2752512 / TPB, TPB, 0, stream>>>(Wih0, Whh0, Wih1, Whh1, ws);
    gather_xe_bf_kernel<<<2097152 / TPB, TPB, 0, stream>>>(x, emb, ws);
    gru_mfma_kernel<<<128, TPB, 0, stream>>>(bih0, bhh0, bih1, bhh1, Wfc, bfc, out, ws);
  } else {
    int*    bar = (int*)ws;
    float4* A0  = (float4*)(ws + A_OFF);
    float4* A1  = (float4*)(ws + A_OFF + HBUF_BYTES);
    float4* B0  = (float4*)(ws + B_OFF);
    float4* B1  = (float4*)(ws + B_OFF + HBUF_BYTES);
    float4* xe4 = (float4*)(ws + XE_OFF);
    const int use_xe = (ws_size >= (size_t)XE_OFF + XE_BYTES) ? 1 : 0;
    hipMemsetAsync(ws, 0, XE_OFF, stream);
    if (use_xe){
      gather_xe_kernel<<<(S_LEN * 64 * BATCH) / TPB, TPB, 0, stream>>>(x, emb, xe4);
    }
    gru_persist_kernel<<<256, TPB, 0, stream>>>(
        x, emb, Wih0, Whh0, bih0, bhh0, Wih1, Whh1, bih1, bhh1, Wfc, bfc,
        out, bar, A0, A1, B0, B1, xe4, use_xe);
  }
}